// Round 5
// baseline (76.652 us; speedup 1.0000x reference)
//
#include <hip/hip_runtime.h>

#define H       128
#define NPTS    512
#define NBATCH  4

// ---- kernel-1 geometry: 256 blocks x 512 thr (8 waves), 4 samples/wave ----
#define K1_BLOCK 512
#define K1_WAVES 8
#define PW       4

// ---- kernel-2 geometry (unchanged, verified) ----
#define BLOCK   256
#define WAVES   4

// ---- distance->magnitude table ----
// t = log2(dist_safe), dist_safe in [1e-4, 50] (the reference's clip range).
// TSAMP samples t_k = T0 + k*TRANGE/TIVL, k = 0..TIVL; TIVL intervals.
#define TSAMP   8192
#define TIVL    8191
#define T0      (-13.2877123795f)
#define TRANGE  (18.9315685693f)

__device__ __forceinline__ float fast_rcp(float x) { return __builtin_amdgcn_rcpf(x); }

__device__ __forceinline__ float silu_f(float x) {
    float e = __expf(-x);
    return x * fast_rcp(1.0f + e);
}

// ============================================================================
// Kernel 1: build magnitude table. 256 blocks x 512 thr; block owns 32 samples
// (4 per wave, 8 waves) -> 2 waves/SIMD so DS and VALU pipes overlap across
// waves (the round-4 version ran 1 wave/SIMD and serialized them).
// W2 staged once per block in LDS (64 KB); layer-1 compute hoisted BEFORE the
// staging barrier so the expf/silu chain hides the W2 load latency.
// tab duplicated: tab[2k] = g_k, tab[2k+1] = g_{k+1} (one dwordx2 per lookup).
// After the full 64-lane butterfly every lane holds all 4 sums, so lanes 0..7
// emit one coalesced 32B store per wave.
// ============================================================================
__global__ __launch_bounds__(K1_BLOCK) void build_mag_table(
    const float* __restrict__ W1, const float* __restrict__ b1,
    const float* __restrict__ W2, const float* __restrict__ b2,
    const float* __restrict__ W3, const float* __restrict__ b3,
    float* __restrict__ tab)
{
    __shared__ float W2s[H * H];                 // 64 KB
    __shared__ float h1s[K1_WAVES][H][PW];       // 8 KB (per-wave private)

    const int tid  = threadIdx.x;
    const int lane = tid & 63;
    const int w    = tid >> 6;

    // ---- issue W2 staging (coalesced float4) ----
    {
        const float4* src = (const float4*)W2;
        float4* dst = (float4*)W2s;
        #pragma unroll
        for (int r = 0; r < (H * H / 4) / K1_BLOCK; ++r)
            dst[r * K1_BLOCK + tid] = src[r * K1_BLOCK + tid];
    }

    const float b3v = b3[0];
    const int base  = blockIdx.x * (K1_WAVES * PW) + w * PW;  // 256*32 = 8192

    // ---- sample geometry + layer 1 BEFORE the barrier (overlaps staging).
    // h1s[w] is written AND read only by wave w -> no barrier needed for it. ----
    float d4[PW], in4[PW];
    #pragma unroll
    for (int p = 0; p < PW; ++p) {
        float t  = fmaf((float)(base + p), TRANGE / (float)TIVL, T0);
        float d  = exp2f(t);
        float ds = fminf(fmaxf(d, 1e-4f), 50.0f);
        d4[p]  = ds;
        in4[p] = 1.0f / ds;
    }

    #pragma unroll
    for (int kk = 0; kk < 2; ++kk) {
        const int ch = lane + kk * 64;
        const float wa = W1[ch], wb = W1[H + ch], bb = b1[ch];  // L2-resident, 1 KB
        float v[PW];
        #pragma unroll
        for (int p = 0; p < PW; ++p)
            v[p] = silu_f(fmaf(d4[p], wa, fmaf(in4[p], wb, bb)));
        *(float4*)&h1s[w][ch][0] = make_float4(v[0], v[1], v[2], v[3]);
    }

    __syncthreads();                              // W2s ready

    // ---- layer 2: lane owns channels k0, k0+1; all operands from LDS ----
    const int k0 = 2 * lane;
    float acc0[PW], acc1[PW];
    #pragma unroll
    for (int p = 0; p < PW; ++p) { acc0[p] = 0.f; acc1[p] = 0.f; }

    #pragma unroll 8
    for (int j = 0; j < H; ++j) {
        const float4 ha = *(const float4*)&h1s[w][j][0];      // broadcast (free)
        const float2 ww = *(const float2*)&W2s[j * H + k0];   // 2-way (free)
        const float wx = ww.x, wy = ww.y;
        acc0[0] = fmaf(ha.x, wx, acc0[0]); acc1[0] = fmaf(ha.x, wy, acc1[0]);
        acc0[1] = fmaf(ha.y, wx, acc0[1]); acc1[1] = fmaf(ha.y, wy, acc1[1]);
        acc0[2] = fmaf(ha.z, wx, acc0[2]); acc1[2] = fmaf(ha.z, wy, acc1[2]);
        acc0[3] = fmaf(ha.w, wx, acc0[3]); acc1[3] = fmaf(ha.w, wy, acc1[3]);
    }

    // ---- layer 3 + full-wave butterfly ----
    const float b20 = b2[k0], b21 = b2[k0 + 1];
    const float w30 = W3[k0], w31 = W3[k0 + 1];
    float part[PW];
    #pragma unroll
    for (int p = 0; p < PW; ++p)
        part[p] = silu_f(acc0[p] + b20) * w30 + silu_f(acc1[p] + b21) * w31;

    #pragma unroll
    for (int off = 32; off >= 1; off >>= 1) {
        #pragma unroll
        for (int p = 0; p < PW; ++p)
            part[p] += __shfl_xor(part[p], off);
    }

    // ---- coalesced table store: wave covers tab[2*base-1 .. 2*base+6].
    // index 2k -> g_k (tab2[k].x), index 2k-1 -> g_k (tab2[k-1].y);
    // lane L -> index 2*base-1+L, sample p = L>>1. Identical values/coverage
    // to the verified scalar version; tab2[TIVL] is never read. ----
    if (lane < 2 * PW) {
        const int idx = 2 * base - 1 + lane;
        if (idx >= 0) tab[idx] = part[lane >> 1] + b3v;
    }
}

// ============================================================================
// Kernel 2: forces. 512 blocks x 256 thr; one ROW per wave (64 lanes x 8 j).
// (byte-identical to the round-4 verified version)
// ============================================================================
__global__ __launch_bounds__(BLOCK) void eval_forces(
    const float* __restrict__ pos, const float* __restrict__ tab,
    float* __restrict__ out)
{
    __shared__ float poss[NPTS * 3];

    const int tid  = threadIdx.x;
    const int lane = tid & 63;
    const int w    = tid >> 6;
    const int row  = blockIdx.x * WAVES + w;     // 512*4 = 2048 rows
    const int b    = row >> 9;                   // same for all 4 waves (4 | 512)
    const int i    = row & (NPTS - 1);

    {
        const float4* src = (const float4*)(pos + b * NPTS * 3);
        float4* dst = (float4*)poss;
        for (int r = tid; r < NPTS * 3 / 4; r += BLOCK) dst[r] = src[r];
    }
    __syncthreads();

    const float pix = poss[3 * i + 0];
    const float piy = poss[3 * i + 1];
    const float piz = poss[3 * i + 2];

    const float INVH = (float)TIVL / TRANGE;
    const float XOFF = -T0 * ((float)TIVL / TRANGE);
    const float2* tab2 = (const float2*)tab;

    float fx = 0.f, fy = 0.f, fz = 0.f;

    #pragma unroll
    for (int k = 0; k < NPTS / 64; ++k) {
        const int j = lane + 64 * k;
        const float dx = pix - poss[3 * j + 0];
        const float dy = piy - poss[3 * j + 1];
        const float dz = piz - poss[3 * j + 2];
        const float s  = fmaf(dx, dx, fmaf(dy, dy, dz * dz));
        const bool ok  = (s > 0.0f) && (j != i);
        const float rs = __builtin_amdgcn_rsqf(fmaxf(s, 1e-30f));
        const float d  = s * rs;
        const float ds = fminf(fmaxf(d, 1e-4f), 50.0f);
        float x = fmaf(__log2f(ds), INVH, XOFF);
        x = fminf(fmaxf(x, 0.0f), (float)TIVL - 0.001f);
        const int   kk = (int)x;
        const float fr = x - (float)kk;
        const float2 g = tab2[kk];
        const float mag = fmaf(fr, g.y - g.x, g.x);
        const float f   = ok ? mag * fminf(rs, 1e6f) : 0.0f;
        fx = fmaf(f, dx, fx);
        fy = fmaf(f, dy, fy);
        fz = fmaf(f, dz, fz);
    }

    #pragma unroll
    for (int off = 32; off >= 1; off >>= 1) {
        fx += __shfl_xor(fx, off);
        fy += __shfl_xor(fy, off);
        fz += __shfl_xor(fz, off);
    }
    if (lane == 0) {
        out[row * 3 + 0] = fx;
        out[row * 3 + 1] = fy;
        out[row * 3 + 2] = fz;
    }
}

extern "C" void kernel_launch(void* const* d_in, const int* in_sizes, int n_in,
                              void* d_out, int out_size, void* d_ws, size_t ws_size,
                              hipStream_t stream) {
    const float* pos = (const float*)d_in[0];
    const float* W1  = (const float*)d_in[1];
    const float* b1  = (const float*)d_in[2];
    const float* W2  = (const float*)d_in[3];
    const float* b2  = (const float*)d_in[4];
    const float* W3  = (const float*)d_in[5];
    const float* b3  = (const float*)d_in[6];
    float* out = (float*)d_out;
    float* tab = (float*)d_ws;

    hipLaunchKernelGGL(build_mag_table, dim3(TSAMP / (K1_WAVES * PW)), dim3(K1_BLOCK), 0, stream,
                       W1, b1, W2, b2, W3, b3, tab);
    hipLaunchKernelGGL(eval_forces, dim3(NBATCH * NPTS / WAVES), dim3(BLOCK), 0, stream,
                       pos, tab, out);
}